// Round 1
// baseline (1690.785 us; speedup 1.0000x reference)
//
#include <hip/hip_runtime.h>
#include <math.h>

#define WAYS 32
#define NTOT 2048
#define XD 84
#define CIN 3
#define C1 10
#define C2 10
#define P1W 40      // p1 cols actually needed (col 40 feeds only dropped pool col)
#define NQMAX 16    // max p1 rows per band
#define NXMAX 34    // max x rows per band
#define FLAT 3610
#define KSPLIT 16
#define KCHUNK 226  // ceil(3610/16)

__device__ __forceinline__ float softplus_f(float x) {
    return (x > 20.f) ? x : log1pf(expf(x));
}
__device__ __forceinline__ float kl_f(float mu, float sd) {
    return -logf(sd) + 0.5f * (sd * sd + mu * mu) - 0.5f;
}

// ---------------------------------------------------------------------------
// Fused conv1+relu+pool -> conv2+relu+pool, per (image, row-band) block.
// Bands over p2 rows: [0,7), [7,13), [13,19).
// ---------------------------------------------------------------------------
__global__ __launch_bounds__(256, 2) void k_conv(
        const float* __restrict__ x,
        const float* __restrict__ w1, const float* __restrict__ b1,
        const float* __restrict__ w2, const float* __restrict__ b2,
        float* __restrict__ p2) {
    __shared__ float xs[CIN * NXMAX * 84];   // 8568 floats
    __shared__ float p1s[C1 * NQMAX * P1W];  // 6400 floats  (59.9 KB total)

    int img  = blockIdx.x / 3;
    int band = blockIdx.x % 3;
    int r0 = (band == 0) ? 0 : (band == 1 ? 7 : 13);
    int r1 = (band == 0) ? 7 : (band == 1 ? 13 : 19);
    int q0 = 2 * r0;
    int q1 = 2 * r1 + 1; if (q1 > 39) q1 = 39;
    int nq  = q1 - q0 + 1;          // <= 16
    int xr0 = 2 * q0;
    int xr1 = 2 * q1 + 3;           // <= 81
    int nxr = xr1 - xr0 + 1;        // <= 34
    int tid = threadIdx.x;

    // ---- stage x band into LDS (coalesced) ----
    const float* xg = x + (size_t)img * (CIN * XD * XD);
    int tot = CIN * nxr * 84;
    for (int i = tid; i < tot; i += 256) {
        int c   = i / (nxr * 84);
        int rem = i - c * (nxr * 84);
        int r   = rem / 84;
        int col = rem - r * 84;
        xs[c * (NXMAX * 84) + r * 84 + col] =
            xg[c * (XD * XD) + (xr0 + r) * 84 + col];
    }
    __syncthreads();

    // ---- conv1 + relu + 2x2 maxpool -> p1s ----
    int npos1 = nq * P1W;
    for (int p = tid; p < npos1; p += 256) {
        int qr = p / P1W;
        int pc = p - qr * P1W;
        float best[C1];
        #pragma unroll
        for (int o = 0; o < C1; o++) best[o] = -1e30f;
        #pragma unroll
        for (int dy = 0; dy < 2; dy++) {
            #pragma unroll
            for (int dx = 0; dx < 2; dx++) {
                float acc[C1];
                #pragma unroll
                for (int o = 0; o < C1; o++) acc[o] = 0.f;
                int cr = 2 * (q0 + qr) + dy;    // abs conv row
                int cc = 2 * pc + dx;           // abs conv col
                int xr = cr - xr0;              // rel x row
                #pragma unroll
                for (int c = 0; c < CIN; c++) {
                    #pragma unroll
                    for (int ky = 0; ky < 3; ky++) {
                        #pragma unroll
                        for (int kx = 0; kx < 3; kx++) {
                            float xv = xs[c * (NXMAX * 84) + (xr + ky) * 84 + (cc + kx)];
                            #pragma unroll
                            for (int o = 0; o < C1; o++)
                                acc[o] = fmaf(xv, w1[((o * CIN + c) * 3 + ky) * 3 + kx], acc[o]);
                        }
                    }
                }
                #pragma unroll
                for (int o = 0; o < C1; o++) best[o] = fmaxf(best[o], acc[o]);
            }
        }
        #pragma unroll
        for (int o = 0; o < C1; o++)
            p1s[o * (NQMAX * P1W) + qr * P1W + pc] = fmaxf(best[o] + b1[o], 0.f);
    }
    __syncthreads();

    // ---- conv2 + relu + 2x2 maxpool -> p2 (global) ----
    // item space: (pos, half) with half wave-uniform; 5 output channels per item.
    int npos = (r1 - r0) * 19;      // <= 133
    for (int it = tid; it < 512; it += 256) {
        int pos  = (it & 127) + ((it >> 8) << 7);
        int half = (it >> 7) & 1;
        if (pos >= npos) continue;
        int half_u = __builtin_amdgcn_readfirstlane(half);  // wave-uniform -> s_load weights
        int prr = pos / 19;
        int pc  = pos - prr * 19;
        int pr  = r0 + prr;          // abs p2 row
        float best[5];
        #pragma unroll
        for (int o = 0; o < 5; o++) best[o] = -1e30f;
        #pragma unroll
        for (int dy = 0; dy < 2; dy++) {
            #pragma unroll
            for (int dx = 0; dx < 2; dx++) {
                float acc[5];
                #pragma unroll
                for (int o = 0; o < 5; o++) acc[o] = 0.f;
                int cr = 2 * pr + dy;   // conv2 row -> p1 rows cr..cr+2
                int cc = 2 * pc + dx;
                #pragma unroll
                for (int ic = 0; ic < C2; ic++) {
                    #pragma unroll
                    for (int ky = 0; ky < 3; ky++) {
                        #pragma unroll
                        for (int kx = 0; kx < 3; kx++) {
                            float pv = p1s[ic * (NQMAX * P1W) + (cr + ky - q0) * P1W + (cc + kx)];
                            #pragma unroll
                            for (int o = 0; o < 5; o++) {
                                int oc = half_u * 5 + o;
                                acc[o] = fmaf(pv, w2[((oc * C2 + ic) * 3 + ky) * 3 + kx], acc[o]);
                            }
                        }
                    }
                }
                #pragma unroll
                for (int o = 0; o < 5; o++) best[o] = fmaxf(best[o], acc[o]);
            }
        }
        float* outp = p2 + (size_t)img * FLAT;
        #pragma unroll
        for (int o = 0; o < 5; o++) {
            int oc = half_u * 5 + o;
            outp[oc * 361 + pr * 19 + pc] = fmaxf(best[o] + b2[oc], 0.f);
        }
    }
}

// ---------------------------------------------------------------------------
// labels[n] = argmax(y[n, :])  (first max, matches jnp.argmax on one-hot)
// ---------------------------------------------------------------------------
__global__ void k_label(const float* __restrict__ y, int* __restrict__ label) {
    int n = blockIdx.x * 256 + threadIdx.x;
    if (n >= NTOT) return;
    const float* yr = y + n * WAYS;
    float best = yr[0]; int bi = 0;
    for (int k = 1; k < WAYS; k++) {
        float v = yr[k];
        if (v > best) { best = v; bi = k; }
    }
    label[n] = bi;
}

// ---------------------------------------------------------------------------
// enc GEMM: H[2048,64] += p2[2048,3610] @ enc_w[3610,64]  (split-K, atomics)
// H pre-zeroed; enc_b folded into k_stats.
// ---------------------------------------------------------------------------
__global__ __launch_bounds__(256, 2) void k_enc(
        const float* __restrict__ A, const float* __restrict__ W,
        float* __restrict__ H) {
    __shared__ float a_s[32 * 66];   // A-tile transposed [k][r], pad 66
    __shared__ float w_s[32 * 64];   // W-tile [k][c]
    int mb = blockIdx.x >> 4;        // 32 M-blocks of 64 rows
    int ks = blockIdx.x & 15;
    int row0 = mb * 64;
    int kbeg = ks * KCHUNK;
    int kend = min(kbeg + KCHUNK, FLAT);
    int tid = threadIdx.x;
    int tr = tid & 15, tc = tid >> 4;    // thread tile: rows tr*4.., cols tc*4..
    float acc[4][4] = {};

    for (int k0 = kbeg; k0 < kend; k0 += 32) {
        {
            int kk = tid & 31;
            int r  = tid >> 5;
            int gk = k0 + kk;
            #pragma unroll
            for (int i = 0; i < 8; i++) {
                int rr = r + i * 8;
                float v = (gk < kend) ? A[(size_t)(row0 + rr) * FLAT + gk] : 0.f;
                a_s[kk * 66 + rr] = v;
            }
            int c  = tid & 63;
            int kw = tid >> 6;
            #pragma unroll
            for (int i = 0; i < 8; i++) {
                int kk2 = kw + i * 4;
                int gk2 = k0 + kk2;
                float v = (gk2 < kend) ? W[(size_t)gk2 * 64 + c] : 0.f;
                w_s[kk2 * 64 + c] = v;
            }
        }
        __syncthreads();
        #pragma unroll 8
        for (int k = 0; k < 32; k++) {
            float2 a01 = *(const float2*)&a_s[k * 66 + tr * 4];
            float2 a23 = *(const float2*)&a_s[k * 66 + tr * 4 + 2];
            float4 wv  = *(const float4*)&w_s[k * 64 + tc * 4];
            float av[4]  = {a01.x, a01.y, a23.x, a23.y};
            float wvv[4] = {wv.x, wv.y, wv.z, wv.w};
            #pragma unroll
            for (int i = 0; i < 4; i++)
                #pragma unroll
                for (int j = 0; j < 4; j++)
                    acc[i][j] = fmaf(av[i], wvv[j], acc[i][j]);
        }
        __syncthreads();
    }
    #pragma unroll
    for (int i = 0; i < 4; i++)
        #pragma unroll
        for (int j = 0; j < 4; j++)
            atomicAdd(&H[(size_t)(row0 + tr * 4 + i) * 64 + tc * 4 + j], acc[i][j]);
}

// ---------------------------------------------------------------------------
// Per-class statistics -> cs[32,256] via t1, plus card[32].
// One block per class; bias enc_b folded in here.
// ---------------------------------------------------------------------------
__global__ __launch_bounds__(256) void k_stats(
        const float* __restrict__ H, const float* __restrict__ encb,
        const int* __restrict__ label,
        const float* __restrict__ t1w, const float* __restrict__ t1b,
        float* __restrict__ cs, float* __restrict__ card) {
    __shared__ float rs[4][64], rs2[4][64];
    __shared__ int rc[4];
    int w = blockIdx.x;
    int tid = threadIdx.x;
    int c = tid & 63, g = tid >> 6;
    float s = 0.f, s2 = 0.f; int cnt = 0;
    for (int n = g; n < NTOT; n += 4) {
        if (label[n] == w) {
            float hv = H[n * 64 + c] + encb[c];
            s += hv; s2 += hv * hv; cnt++;
        }
    }
    rs[g][c] = s; rs2[g][c] = s2;
    if (c == 0) rc[g] = cnt;
    __syncthreads();
    if (g == 0) {
        float S  = rs[0][c] + rs[1][c] + rs[2][c] + rs[3][c];
        float S2 = rs2[0][c] + rs2[1][c] + rs2[2][c] + rs2[3][c];
        int CNT  = rc[0] + rc[1] + rc[2] + rc[3];
        float mean = S / 2048.f;
        float var  = (S2 - S * S / 2048.f) / 2047.f;
        float cd   = ((float)CNT - 1.f) / 63.f;
        #pragma unroll
        for (int j = 0; j < 4; j++)
            cs[w * 256 + c * 4 + j] =
                fmaxf(mean * t1w[j] + var * t1w[4 + j] + cd * t1w[8 + j] + t1b[j], 0.f);
        if (c == 0) card[w] = cd;
    }
}

// ---------------------------------------------------------------------------
// Head: te2 MLP, t2, omega/gamma/zeta heads, KL, output. Single block.
// ---------------------------------------------------------------------------
__global__ __launch_bounds__(256) void k_head(
        const float* __restrict__ cs_g, const float* __restrict__ card,
        const float* __restrict__ te2w1, const float* __restrict__ te2b1,
        const float* __restrict__ te2w2, const float* __restrict__ te2b2,
        const float* __restrict__ t2w, const float* __restrict__ t2b,
        const float* __restrict__ omw, const float* __restrict__ omb,
        const float* __restrict__ osw, const float* __restrict__ osb,
        const float* __restrict__ gaw, const float* __restrict__ gab,
        const float* __restrict__ gmw, const float* __restrict__ gmb,
        const float* __restrict__ gsw, const float* __restrict__ gsb,
        const float* __restrict__ zew, const float* __restrict__ zeb,
        const float* __restrict__ zmw, const float* __restrict__ zmb,
        const float* __restrict__ zsw, const float* __restrict__ zsb,
        float* __restrict__ out) {
    __shared__ float cst[256 * 36];  // cs transposed [k][w], pad 36
    __shared__ float a1t[128 * 36];  // a1 transposed [j][w], pad 36
    __shared__ float ts[32 * 32];    // [w][j]
    __shared__ float tv[128];
    __shared__ float eg_s[64], ez_s[64];
    __shared__ float red[256];
    int tid = threadIdx.x;

    // stage cs transposed
    for (int i = tid; i < 32 * 256; i += 256) {
        int w = i >> 8, k = i & 255;
        cst[k * 36 + w] = cs_g[i];
    }
    __syncthreads();

    // a1 = relu(cs @ te2w1 + b1): 4x4 thread tiles over [32 w][128 j]
    {
        int wg = tid >> 5, jg = tid & 31;
        int w0 = wg * 4, j0 = jg * 4;
        float acc[4][4] = {};
        for (int k = 0; k < 256; k++) {
            float4 cv = *(const float4*)&cst[k * 36 + w0];
            float4 wv = *(const float4*)&te2w1[k * 128 + j0];
            float cva[4] = {cv.x, cv.y, cv.z, cv.w};
            float wva[4] = {wv.x, wv.y, wv.z, wv.w};
            #pragma unroll
            for (int i = 0; i < 4; i++)
                #pragma unroll
                for (int j = 0; j < 4; j++)
                    acc[i][j] = fmaf(cva[i], wva[j], acc[i][j]);
        }
        #pragma unroll
        for (int jj = 0; jj < 4; jj++) {
            float b = te2b1[j0 + jj];
            float4 v;
            v.x = fmaxf(acc[0][jj] + b, 0.f);
            v.y = fmaxf(acc[1][jj] + b, 0.f);
            v.z = fmaxf(acc[2][jj] + b, 0.f);
            v.w = fmaxf(acc[3][jj] + b, 0.f);
            *(float4*)&a1t[(j0 + jj) * 36 + w0] = v;
        }
    }
    __syncthreads();

    // ts = a1 @ te2w2 + b2: 2x2 tiles over [32 w][32 j]
    {
        int wg = tid >> 4, jg = tid & 15;
        int w0 = wg * 2, j0 = jg * 2;
        float acc[2][2] = {};
        for (int k = 0; k < 128; k++) {
            float2 av = *(const float2*)&a1t[k * 36 + w0];
            float2 wv = *(const float2*)&te2w2[k * 32 + j0];
            acc[0][0] = fmaf(av.x, wv.x, acc[0][0]);
            acc[0][1] = fmaf(av.x, wv.y, acc[0][1]);
            acc[1][0] = fmaf(av.y, wv.x, acc[1][0]);
            acc[1][1] = fmaf(av.y, wv.y, acc[1][1]);
        }
        #pragma unroll
        for (int i = 0; i < 2; i++)
            #pragma unroll
            for (int j = 0; j < 2; j++)
                ts[(w0 + i) * 32 + (j0 + j)] = acc[i][j] + te2b2[j0 + j];
    }
    __syncthreads();

    float muo = 0.f, sdo = 1.f;   // held by threads 32..63
    // column stats -> tv (threads 0..31); omega heads (threads 32..63)
    if (tid < 32) {
        float csum = 0.f;
        for (int w2 = 0; w2 < 32; w2++) csum += card[w2];
        float s = 0.f, s2 = 0.f;
        for (int w2 = 0; w2 < 32; w2++) { float v = ts[w2 * 32 + tid]; s += v; s2 += v * v; }
        float m  = s / 32.f;
        float vv = (s2 - s * s / 32.f) / 31.f;
        #pragma unroll
        for (int j = 0; j < 4; j++)
            tv[tid * 4 + j] = fmaxf(m * t2w[j] + vv * t2w[4 + j] + csum * t2w[8 + j] + t2b[j], 0.f);
    } else if (tid < 64) {
        int w = tid - 32;
        float am = 0.f, as = 0.f;
        for (int k = 0; k < 256; k++) {
            float cv = cst[k * 36 + w];
            am = fmaf(cv, omw[k], am);
            as = fmaf(cv, osw[k], as);
        }
        muo = fmaxf(am + omb[0], 0.f);
        sdo = softplus_f(fmaxf(as + osb[0], 0.f));
        out[w] = muo;
    }
    __syncthreads();

    // eg, ez (threads 64..127)
    if (tid >= 64 && tid < 128) {
        int j = tid - 64;
        float ag = gab[j], az = zeb[j];
        for (int k = 0; k < 128; k++) {
            float t = tv[k];
            ag = fmaf(t, gaw[k * 64 + j], ag);
            az = fmaf(t, zew[k * 64 + j], az);
        }
        eg_s[j] = fmaxf(ag, 0.f);
        ez_s[j] = fmaxf(az, 0.f);
    }
    __syncthreads();

    // zeta heads (all 256 threads) + gamma heads (threads 0..4) + KL contributions
    float r = 0.f;
    {
        int j = tid;
        float am = zmb[j], as = zsb[j];
        for (int k = 0; k < 64; k++) {
            float e = ez_s[k];
            am = fmaf(e, zmw[k * 256 + j], am);
            as = fmaf(e, zsw[k * 256 + j], as);
        }
        float mu = fmaxf(am, 0.f);
        float sd = softplus_f(fmaxf(as, 0.f));
        out[37 + j] = mu;
        r += kl_f(mu, sd);
    }
    if (tid < 5) {
        float am = gmb[tid], as = gsb[tid];
        for (int k = 0; k < 64; k++) {
            float e = eg_s[k];
            am = fmaf(e, gmw[k * 5 + tid], am);
            as = fmaf(e, gsw[k * 5 + tid], as);
        }
        float mu = fmaxf(am, 0.f);
        float sd = softplus_f(fmaxf(as, 0.f));
        out[32 + tid] = mu;
        r += kl_f(mu, sd);
    }
    if (tid >= 32 && tid < 64) r += kl_f(muo, sdo);
    red[tid] = r;
    __syncthreads();
    for (int s = 128; s > 0; s >>= 1) {
        if (tid < s) red[tid] += red[tid + s];
        __syncthreads();
    }
    if (tid == 0) out[293] = red[0];
}

// ---------------------------------------------------------------------------
extern "C" void kernel_launch(void* const* d_in, const int* in_sizes, int n_in,
                              void* d_out, int out_size, void* d_ws, size_t ws_size,
                              hipStream_t stream) {
    const float* x    = (const float*)d_in[0];
    const float* y    = (const float*)d_in[1];
    const float* w1   = (const float*)d_in[2];
    const float* b1   = (const float*)d_in[3];
    const float* w2   = (const float*)d_in[4];
    const float* b2   = (const float*)d_in[5];
    const float* encw = (const float*)d_in[6];
    const float* encb = (const float*)d_in[7];
    const float* t1w  = (const float*)d_in[8];
    const float* t1b  = (const float*)d_in[9];
    const float* te2w1 = (const float*)d_in[10];
    const float* te2b1 = (const float*)d_in[11];
    const float* te2w2 = (const float*)d_in[12];
    const float* te2b2 = (const float*)d_in[13];
    const float* t2w  = (const float*)d_in[14];
    const float* t2b  = (const float*)d_in[15];
    const float* omw  = (const float*)d_in[16];
    const float* omb  = (const float*)d_in[17];
    const float* osw  = (const float*)d_in[18];
    const float* osb  = (const float*)d_in[19];
    const float* gaw  = (const float*)d_in[20];
    const float* gab  = (const float*)d_in[21];
    const float* gmw  = (const float*)d_in[22];
    const float* gmb  = (const float*)d_in[23];
    const float* gsw  = (const float*)d_in[24];
    const float* gsb  = (const float*)d_in[25];
    const float* zew  = (const float*)d_in[26];
    const float* zeb  = (const float*)d_in[27];
    const float* zmw  = (const float*)d_in[28];
    const float* zmb  = (const float*)d_in[29];
    const float* zsw  = (const float*)d_in[30];
    const float* zsb  = (const float*)d_in[31];
    float* out = (float*)d_out;

    float* p2   = (float*)d_ws;                       // [2048][3610]
    float* H    = p2 + (size_t)NTOT * FLAT;           // [2048][64]
    int*   lbl  = (int*)(H + NTOT * 64);              // [2048]
    float* cs   = (float*)(lbl + NTOT);               // [32][256]
    float* card = cs + 32 * 256;                      // [32]

    hipMemsetAsync(H, 0, NTOT * 64 * sizeof(float), stream);
    hipLaunchKernelGGL(k_conv, dim3(NTOT * 3), dim3(256), 0, stream, x, w1, b1, w2, b2, p2);
    hipLaunchKernelGGL(k_label, dim3(8), dim3(256), 0, stream, y, lbl);
    hipLaunchKernelGGL(k_enc, dim3(32 * KSPLIT), dim3(256), 0, stream, p2, encw, H);
    hipLaunchKernelGGL(k_stats, dim3(32), dim3(256), 0, stream, H, encb, lbl, t1w, t1b, cs, card);
    hipLaunchKernelGGL(k_head, dim3(1), dim3(256), 0, stream, cs, card,
                       te2w1, te2b1, te2w2, te2b2, t2w, t2b,
                       omw, omb, osw, osb, gaw, gab, gmw, gmb, gsw, gsb,
                       zew, zeb, zmw, zmb, zsw, zsb, out);
}